// Round 2
// baseline (814.543 us; speedup 1.0000x reference)
//
#include <hip/hip_runtime.h>
#include <hip/hip_bf16.h>
#include <cstdint>

typedef __attribute__((ext_vector_type(8))) short short8;
typedef __attribute__((ext_vector_type(4))) float f32x4;
typedef _Float16 f16x2 __attribute__((ext_vector_type(2)));

#define NS 512
#define NB 32
#define NE 768
#define NH 128
#define NG 512          // 4*H
#define NT 15
#define NM (NB*NS)      // 16384 rows, m = b*512 + s

__device__ __forceinline__ float fd2(unsigned int wp, unsigned int hp, float acc) {
#if __has_builtin(__builtin_amdgcn_fdot2)
  return __builtin_amdgcn_fdot2(__builtin_bit_cast(f16x2, wp),
                                __builtin_bit_cast(f16x2, hp), acc, false);
#else
  f16x2 a = __builtin_bit_cast(f16x2, wp);
  f16x2 b = __builtin_bit_cast(f16x2, hp);
  return acc + (float)a[0]*(float)b[0] + (float)a[1]*(float)b[1];
#endif
}

__device__ __forceinline__ float bflo(unsigned int u){ return __builtin_bit_cast(float, u << 16); }
__device__ __forceinline__ float bfhi(unsigned int u){ return __builtin_bit_cast(float, u & 0xffff0000u); }
__device__ __forceinline__ float sigf(float x){ return __fdividef(1.f, 1.f + __expf(-x)); }
__device__ __forceinline__ float tanhf_(float x){ return 1.f - __fdividef(2.f, __expf(2.f*x) + 1.f); }

__device__ __forceinline__ void gload16(const void* g, void* l) {
#if __has_builtin(__builtin_amdgcn_global_load_lds)
  __builtin_amdgcn_global_load_lds((const __attribute__((address_space(1))) void*)g,
                                   (__attribute__((address_space(3))) void*)l, 16, 0, 0);
#else
  *(uint4*)l = *(const uint4*)g;
#endif
}

// ---------------- converts ----------------
__global__ void cvt_bf16_kernel(const float* __restrict__ in,
                                __hip_bfloat16* __restrict__ out, int n4) {
  int i = blockIdx.x*blockDim.x + threadIdx.x;
  int stride = gridDim.x*blockDim.x;
  for (int j = i; j < n4; j += stride) {
    float4 v = ((const float4*)in)[j];
    __hip_bfloat16 h0 = __float2bfloat16(v.x), h1 = __float2bfloat16(v.y),
                   h2 = __float2bfloat16(v.z), h3 = __float2bfloat16(v.w);
    ushort4 o;
    o.x = __builtin_bit_cast(unsigned short, h0);
    o.y = __builtin_bit_cast(unsigned short, h1);
    o.z = __builtin_bit_cast(unsigned short, h2);
    o.w = __builtin_bit_cast(unsigned short, h3);
    ((ushort4*)out)[j] = o;
  }
}

__global__ void cvt_f16_kernel(const float* __restrict__ in,
                               _Float16* __restrict__ out, int n4) {
  int i = blockIdx.x*blockDim.x + threadIdx.x;
  int stride = gridDim.x*blockDim.x;
  for (int j = i; j < n4; j += stride) {
    float4 v = ((const float4*)in)[j];
    _Float16 h0 = (_Float16)v.x, h1 = (_Float16)v.y,
             h2 = (_Float16)v.z, h3 = (_Float16)v.w;
    ushort4 o;
    o.x = __builtin_bit_cast(unsigned short, h0);
    o.y = __builtin_bit_cast(unsigned short, h1);
    o.z = __builtin_bit_cast(unsigned short, h2);
    o.w = __builtin_bit_cast(unsigned short, h3);
    ((ushort4*)out)[j] = o;
  }
}

__global__ void bias_kernel(const float* __restrict__ bihf, const float* __restrict__ bhhf,
                            const float* __restrict__ bihb, const float* __restrict__ bhhb,
                            float* __restrict__ bias) {
  int i = blockIdx.x*blockDim.x + threadIdx.x;
  if (i < 512)       bias[i] = bihf[i] + bhhf[i];
  else if (i < 1024) bias[i] = bihb[i-512] + bhhb[i-512];
}

// ---------------- xproj GEMM: [16384x768]bf16 @ [1024x768]^T bf16 -> packed-gate bf16 ----------------
// 128x128 tile, BK=64, 4 waves (2x2), global_load_lds width-16 staging.
// Output layout per dir: xq[m][j*4+gate]  (j = h-idx 0..127, gate 0..3 = i,f,g,o)
__global__ __launch_bounds__(256, 2) void gemm_xproj(
    const __hip_bfloat16* __restrict__ A,    // [NM][768]
    const __hip_bfloat16* __restrict__ Bw,   // [1024][768] rows n (B^T layout)
    const float* __restrict__ bias,          // [1024]
    __hip_bfloat16* __restrict__ xqF,        // [NM][512] packed-gate
    __hip_bfloat16* __restrict__ xqB)        // [NM][512] packed-gate
{
  __shared__ __align__(16) __hip_bfloat16 As[128*64];
  __shared__ __align__(16) __hip_bfloat16 Bs[128*64];
  const int bm = blockIdx.x * 128;
  const int bn = blockIdx.y * 128;
  const int tid = threadIdx.x;
  const int lane = tid & 63;
  const int wv = tid >> 6;
  const int wr = wv >> 1, wc = wv & 1;
  char* AsB = (char*)As;
  char* BsB = (char*)Bs;
  const char* Ab = (const char*)A;
  const char* Bb = (const char*)Bw;
  f32x4 acc[4][4] = {};

  for (int kt = 0; kt < 12; ++kt) {
    const int k0 = kt * 64;
    __syncthreads();                  // prev compute done before overwrite
    #pragma unroll
    for (int i = 0; i < 4; ++i) {
      int fb = i*4096 + tid*16;       // byte within 16KB tile
      int r  = fb >> 7;               // row (128B per row of 64 bf16)
      int cb = fb & 127;              // byte within row
      gload16(Ab + ((size_t)(bm + r)*768 + k0)*2 + cb, AsB + fb);
      gload16(Bb + ((size_t)(bn + r)*768 + k0)*2 + cb, BsB + fb);
    }
    __syncthreads();                  // vmcnt(0) drained by compiler before barrier
    #pragma unroll
    for (int ks = 0; ks < 2; ++ks) {
      const int krow = ks*32 + ((lane >> 4) << 3);
      short8 af[4], bfr[4];
      #pragma unroll
      for (int m = 0; m < 4; ++m) {
        int row = wr*64 + m*16 + (lane & 15);
        af[m] = *(const short8*)(AsB + (row*64 + krow)*2);
      }
      #pragma unroll
      for (int n = 0; n < 4; ++n) {
        int row = wc*64 + n*16 + (lane & 15);
        bfr[n] = *(const short8*)(BsB + (row*64 + krow)*2);
      }
      #pragma unroll
      for (int m = 0; m < 4; ++m)
        #pragma unroll
        for (int n = 0; n < 4; ++n)
          acc[m][n] = __builtin_amdgcn_mfma_f32_16x16x32_bf16(af[m], bfr[n], acc[m][n], 0, 0, 0);
    }
  }
  // epilogue with packed-gate permute: orig col c (within dir) -> (c&127)*4 + (c>>7)
  #pragma unroll
  for (int m = 0; m < 4; ++m) {
    #pragma unroll
    for (int n = 0; n < 4; ++n) {
      const int col = bn + wc*64 + n*16 + (lane & 15);
      const float bv = bias[col];
      const int cc = col & 511;
      const int widx = (cc & 127)*4 + (cc >> 7);
      __hip_bfloat16* dst = (col < 512) ? xqF : xqB;
      #pragma unroll
      for (int jj = 0; jj < 4; ++jj) {
        const int row = bm + wr*64 + m*16 + ((lane >> 4)*4 + jj);
        dst[(size_t)row*512 + widx] = __float2bfloat16(acc[m][n][jj] + bv);
      }
    }
  }
}

// ---------------- LSTM recurrence: 64 blocks = (dir, b) chains ----------------
// 256 threads: thread = (quad j0 = t>>2, k-quarter q = t&3).
// Thread computes all 4 gates for h-indices {j0, j0+64} over k in [q*32, q*32+32),
// butterfly shfl_xor(1,2) completes the k-reduction within the quad.
__global__ __launch_bounds__(256, 1) void lstm_kernel(
    const __hip_bfloat16* __restrict__ xq,   // [2][NM][512] packed-gate
    const _Float16* __restrict__ whh16,      // [2][512][128]
    float* __restrict__ hf,                  // [NM][128]
    float* __restrict__ hb)                  // [NM][128]
{
  __shared__ __align__(16) _Float16 hsh[2][128];
  const int bid = blockIdx.x;
  const int dir = bid >> 5, b = bid & 31;
  const int t = threadIdx.x;
  const int quad = t >> 2, q = t & 3;
  const int j0 = quad, j1 = quad + 64;

  // weights: 8 rows (4 gates x {j0,j1}) x 16 f16-pairs of this thread's k-quarter
  unsigned int wq[8][16];
  #pragma unroll
  for (int u = 0; u < 8; ++u) {
    const int g = u >> 1;
    const int jj = (u & 1) ? j1 : j0;
    const uint4* wp = (const uint4*)(whh16 + ((size_t)dir*512 + g*128 + jj)*128 + q*32);
    #pragma unroll
    for (int i = 0; i < 4; ++i) {
      uint4 v = wp[i];
      wq[u][i*4+0] = v.x; wq[u][i*4+1] = v.y; wq[u][i*4+2] = v.z; wq[u][i*4+3] = v.w;
    }
  }
  // pin in VGPRs: forbid rematerialization of the loads inside the loop
  #pragma unroll
  for (int u = 0; u < 8; ++u)
    #pragma unroll
    for (int p = 0; p < 16; ++p)
      asm volatile("" : "+v"(wq[u][p]));

  if (t < 128) hsh[0][t] = (_Float16)0.f;
  __syncthreads();

  const __hip_bfloat16* xp = xq + ((size_t)dir*NM + (size_t)b*512)*512;
  float* hout = (dir ? hb : hf) + (size_t)b*512*128;

  float c0 = 0.f, c1 = 0.f;
  int rb = 0;

  const int s0 = dir ? 511 : 0;
  uint2 xa = *(const uint2*)(xp + (size_t)s0*512 + j0*4);
  uint2 xb = *(const uint2*)(xp + (size_t)s0*512 + j1*4);

  for (int si = 0; si < 512; ++si) {
    const int s = dir ? (511 - si) : si;
    const uint2 cxa = xa, cxb = xb;
    if (si < 511) {                      // prefetch next step early (covers L2/L3 latency)
      const int sn = dir ? (510 - si) : (si + 1);
      xa = *(const uint2*)(xp + (size_t)sn*512 + j0*4);
      xb = *(const uint2*)(xp + (size_t)sn*512 + j1*4);
    }
    // h quarter from LDS
    const uint4* h4 = (const uint4*)((const _Float16*)hsh + rb*128 + q*32);
    uint4 hA = h4[0], hB = h4[1], hC = h4[2], hD = h4[3];
    unsigned int hq[16] = {hA.x,hA.y,hA.z,hA.w, hB.x,hB.y,hB.z,hB.w,
                           hC.x,hC.y,hC.z,hC.w, hD.x,hD.y,hD.z,hD.w};
    float a0=0.f,a1=0.f,a2=0.f,a3=0.f,a4=0.f,a5=0.f,a6=0.f,a7=0.f;
    #pragma unroll
    for (int p = 0; p < 16; ++p) {
      const unsigned int hv = hq[p];
      a0 = fd2(wq[0][p], hv, a0);
      a1 = fd2(wq[1][p], hv, a1);
      a2 = fd2(wq[2][p], hv, a2);
      a3 = fd2(wq[3][p], hv, a3);
      a4 = fd2(wq[4][p], hv, a4);
      a5 = fd2(wq[5][p], hv, a5);
      a6 = fd2(wq[6][p], hv, a6);
      a7 = fd2(wq[7][p], hv, a7);
    }
    // butterfly k-reduction within quad (all 4 lanes end bit-identical)
    a0 += __shfl_xor(a0, 1, 64); a1 += __shfl_xor(a1, 1, 64);
    a2 += __shfl_xor(a2, 1, 64); a3 += __shfl_xor(a3, 1, 64);
    a4 += __shfl_xor(a4, 1, 64); a5 += __shfl_xor(a5, 1, 64);
    a6 += __shfl_xor(a6, 1, 64); a7 += __shfl_xor(a7, 1, 64);
    a0 += __shfl_xor(a0, 2, 64); a1 += __shfl_xor(a1, 2, 64);
    a2 += __shfl_xor(a2, 2, 64); a3 += __shfl_xor(a3, 2, 64);
    a4 += __shfl_xor(a4, 2, 64); a5 += __shfl_xor(a5, 2, 64);
    a6 += __shfl_xor(a6, 2, 64); a7 += __shfl_xor(a7, 2, 64);

    // z = recurrent + xproj (bias folded in); packed order i,f,g,o
    const float zi0 = a0 + bflo(cxa.x), zf0 = a2 + bfhi(cxa.x);
    const float zg0 = a4 + bflo(cxa.y), zo0 = a6 + bfhi(cxa.y);
    const float zi1 = a1 + bflo(cxb.x), zf1 = a3 + bfhi(cxb.x);
    const float zg1 = a5 + bflo(cxb.y), zo1 = a7 + bfhi(cxb.y);

    c0 = sigf(zf0)*c0 + sigf(zi0)*tanhf_(zg0);
    const float h0 = sigf(zo0)*tanhf_(c0);
    c1 = sigf(zf1)*c1 + sigf(zi1)*tanhf_(zg1);
    const float h1 = sigf(zo1)*tanhf_(c1);

    const int wb = rb ^ 1;
    if (q < 2) hsh[wb][q ? j1 : j0] = (_Float16)(q ? h1 : h0);
    __syncthreads();                    // single barrier per step
    if (q == 2)      hout[(size_t)s*128 + j0] = h0;
    else if (q == 3) hout[(size_t)s*128 + j1] = h1;
    rb = wb;
  }
}

// ---------------- emissions: em[m][t] = [hf|hb][m] . Wp[t] + bp[t] ----------------
__global__ __launch_bounds__(256) void em_kernel(
    const float* __restrict__ hf, const float* __restrict__ hb,
    const float* __restrict__ Wp, const float* __restrict__ bp,
    float* __restrict__ em)
{
  __shared__ float wps[15*256];
  __shared__ float bps[15];
  const int tid = threadIdx.x;
  for (int i = tid; i < 15*256; i += 256) wps[i] = Wp[i];
  if (tid < 15) bps[tid] = bp[tid];
  __syncthreads();
  const size_t m = (size_t)blockIdx.x*256 + tid;
  float acc[15];
  #pragma unroll
  for (int t2 = 0; t2 < 15; ++t2) acc[t2] = bps[t2];
  const float4* hf4 = (const float4*)(hf + m*128);
  const float4* hb4 = (const float4*)(hb + m*128);
  for (int kc = 0; kc < 32; ++kc) {
    float4 hv = hf4[kc];
    #pragma unroll
    for (int t2 = 0; t2 < 15; ++t2)
      acc[t2] += hv.x*wps[t2*256 + kc*4+0] + hv.y*wps[t2*256 + kc*4+1]
               + hv.z*wps[t2*256 + kc*4+2] + hv.w*wps[t2*256 + kc*4+3];
  }
  for (int kc = 0; kc < 32; ++kc) {
    float4 hv = hb4[kc];
    #pragma unroll
    for (int t2 = 0; t2 < 15; ++t2)
      acc[t2] += hv.x*wps[t2*256 + 128 + kc*4+0] + hv.y*wps[t2*256 + 128 + kc*4+1]
               + hv.z*wps[t2*256 + 128 + kc*4+2] + hv.w*wps[t2*256 + 128 + kc*4+3];
  }
  float* eo = em + m*15;
  #pragma unroll
  for (int t2 = 0; t2 < 15; ++t2) eo[t2] = acc[t2];
}

// ---------------- CRF NLL: one block (1 wave) per batch ----------------
__global__ __launch_bounds__(64) void crf_kernel(
    const float* __restrict__ em,    // [NM][15]
    const int* __restrict__ tags, const int* __restrict__ mask,
    const float* __restrict__ trans, const float* __restrict__ start_t,
    const float* __restrict__ end_t, float* __restrict__ out)
{
  __shared__ __align__(16) float ems[512*15];
  __shared__ float trs[225];
  __shared__ int tgs[512];
  __shared__ int mks[512];
  const int b = blockIdx.x, j = threadIdx.x;
  const float* emb = em + (size_t)b*512*15;
  {
    const float4* s4 = (const float4*)emb;
    float4* d4 = (float4*)ems;
    for (int i = j; i < 512*15/4; i += 64) d4[i] = s4[i];
    for (int i = j; i < 512; i += 64) { tgs[i] = tags[b*512+i]; mks[i] = mask[b*512+i]; }
    for (int i = j; i < 225; i += 64) trs[i] = trans[i];
  }
  __syncthreads();

  float trc[15];
  #pragma unroll
  for (int i = 0; i < 15; ++i) trc[i] = (j < 15) ? trs[i*15 + j] : 0.f;

  float alpha = (j < 15) ? (start_t[j] + ems[j]) : -3.0e38f;
  for (int s = 1; s < 512; ++s) {
    const float emv = (j < 15) ? ems[s*15 + j] : 0.f;
    const int msk = mks[s];
    float v[15];
    #pragma unroll
    for (int i = 0; i < 15; ++i) {
      const float ai = __shfl(alpha, i, 64);
      v[i] = ai + trc[i];
    }
    // tree max (depth 4)
    const float t01 = fmaxf(v[0], v[1]),  t23 = fmaxf(v[2], v[3]);
    const float t45 = fmaxf(v[4], v[5]),  t67 = fmaxf(v[6], v[7]);
    const float t89 = fmaxf(v[8], v[9]),  tab = fmaxf(v[10], v[11]);
    const float tcd = fmaxf(v[12], v[13]);
    const float q0 = fmaxf(t01, t23), q1 = fmaxf(t45, t67);
    const float q2 = fmaxf(t89, tab), q3 = fmaxf(tcd, v[14]);
    const float mx = fmaxf(fmaxf(q0, q1), fmaxf(q2, q3));
    // tree sum of exp
    float e[15];
    #pragma unroll
    for (int i = 0; i < 15; ++i) e[i] = __expf(v[i] - mx);
    const float s01 = e[0]+e[1], s23 = e[2]+e[3], s45 = e[4]+e[5], s67 = e[6]+e[7];
    const float s89 = e[8]+e[9], sab = e[10]+e[11], scd = e[12]+e[13];
    const float u0 = s01+s23, u1 = s45+s67, u2 = s89+sab, u3 = scd+e[14];
    const float sum = (u0+u1) + (u2+u3);
    const float nxt = emv + mx + __logf(sum);
    if (msk > 0 && j < 15) alpha = nxt;
  }
  float vz = (j < 15) ? (alpha + end_t[j]) : -3.0e38f;
  float mz = vz;
  #pragma unroll
  for (int off = 32; off > 0; off >>= 1) mz = fmaxf(mz, __shfl_xor(mz, off, 64));
  float se = (j < 15) ? __expf(vz - mz) : 0.f;
  #pragma unroll
  for (int off = 32; off > 0; off >>= 1) se += __shfl_xor(se, off, 64);
  const float logZ = mz + __logf(se);

  float sc = 0.f; int cnt = 0;
  for (int s = j; s < 512; s += 64) cnt += (mks[s] ? 1 : 0);
  for (int s = 1 + j; s < 512; s += 64) {
    if (mks[s]) {
      const int tp = tgs[s-1], tc = tgs[s];
      sc += trs[tp*15 + tc] + ems[s*15 + tc];
    }
  }
  #pragma unroll
  for (int off = 32; off > 0; off >>= 1) {
    sc  += __shfl_xor(sc, off, 64);
    cnt += __shfl_xor(cnt, off, 64);
  }
  if (j == 0) {
    const int t0 = tgs[0];
    sc += start_t[t0] + ems[t0];
    int last = cnt - 1; if (last < 0) last = 0;
    sc += end_t[tgs[last]];
    atomicAdd(out, logZ - sc);
  }
}

// ---------------- launch ----------------
extern "C" void kernel_launch(void* const* d_in, const int* in_sizes, int n_in,
                              void* d_out, int out_size, void* d_ws, size_t ws_size,
                              hipStream_t stream) {
  const float* x      = (const float*)d_in[0];
  const int*   tags   = (const int*)d_in[1];
  const int*   mask   = (const int*)d_in[2];
  const float* Wih_f  = (const float*)d_in[3];
  const float* Whh_f  = (const float*)d_in[4];
  const float* bih_f  = (const float*)d_in[5];
  const float* bhh_f  = (const float*)d_in[6];
  const float* Wih_b  = (const float*)d_in[7];
  const float* Whh_b  = (const float*)d_in[8];
  const float* bih_b  = (const float*)d_in[9];
  const float* bhh_b  = (const float*)d_in[10];
  const float* Wp     = (const float*)d_in[11];
  const float* bp     = (const float*)d_in[12];
  const float* trans  = (const float*)d_in[13];
  const float* start_t= (const float*)d_in[14];
  const float* end_t  = (const float*)d_in[15];
  float* out = (float*)d_out;

  char* ws = (char*)d_ws;
  size_t off = 0;
  auto alloc = [&](size_t bytes) { char* p = ws + off; off += (bytes + 255) & ~(size_t)255; return p; };
  __hip_bfloat16* xbf   = (__hip_bfloat16*)alloc((size_t)NM*NE*2);
  __hip_bfloat16* Wihbf = (__hip_bfloat16*)alloc((size_t)1024*NE*2);
  _Float16*       whh16 = (_Float16*)alloc((size_t)2*512*128*2);
  float*          bias  = (float*)alloc(1024*4);
  __hip_bfloat16* xq    = (__hip_bfloat16*)alloc((size_t)2*NM*512*2);
  float*          hf    = (float*)alloc((size_t)NM*128*4);
  float*          hb    = (float*)alloc((size_t)NM*128*4);
  float*          em    = (float*)alloc((size_t)NM*15*4);
  (void)ws_size; (void)in_sizes; (void)n_in;

  hipMemsetAsync(d_out, 0, (size_t)out_size*sizeof(float), stream);

  cvt_bf16_kernel<<<2048, 256, 0, stream>>>(x, xbf, NM*NE/4);
  cvt_bf16_kernel<<<256, 256, 0, stream>>>(Wih_f, Wihbf, 512*768/4);
  cvt_bf16_kernel<<<256, 256, 0, stream>>>(Wih_b, Wihbf + 512*768, 512*768/4);
  cvt_f16_kernel<<<64, 256, 0, stream>>>(Whh_f, whh16, 512*128/4);
  cvt_f16_kernel<<<64, 256, 0, stream>>>(Whh_b, whh16 + 512*128, 512*128/4);
  bias_kernel<<<4, 256, 0, stream>>>(bih_f, bhh_f, bih_b, bhh_b, bias);

  gemm_xproj<<<dim3(128, 8), 256, 0, stream>>>(xbf, Wihbf, bias, xq, xq + (size_t)NM*512);
  lstm_kernel<<<64, 256, 0, stream>>>(xq, whh16, hf, hb);
  em_kernel<<<64, 256, 0, stream>>>(hf, hb, Wp, bp, em);
  crf_kernel<<<32, 64, 0, stream>>>(em, tags, mask, trans, start_t, end_t, out);
}

// Round 3
// 740.001 us; speedup vs baseline: 1.1007x; 1.1007x over previous
//
#include <hip/hip_runtime.h>
#include <hip/hip_bf16.h>
#include <cstdint>

typedef __attribute__((ext_vector_type(8))) short short8;
typedef __attribute__((ext_vector_type(4))) float f32x4;
typedef _Float16 f16x2 __attribute__((ext_vector_type(2)));

#define NS 512
#define NB 32
#define NE 768
#define NH 128
#define NG 512          // 4*H
#define NT 15
#define NM (NB*NS)      // 16384 rows, m = b*512 + s

__device__ __forceinline__ float fd2(unsigned int wp, unsigned int hp, float acc) {
#if __has_builtin(__builtin_amdgcn_fdot2)
  return __builtin_amdgcn_fdot2(__builtin_bit_cast(f16x2, wp),
                                __builtin_bit_cast(f16x2, hp), acc, false);
#else
  f16x2 a = __builtin_bit_cast(f16x2, wp);
  f16x2 b = __builtin_bit_cast(f16x2, hp);
  return acc + (float)a[0]*(float)b[0] + (float)a[1]*(float)b[1];
#endif
}

__device__ __forceinline__ float bfu(unsigned short u){ return __builtin_bit_cast(float, (unsigned)u << 16); }
__device__ __forceinline__ float sigf(float x){ return __fdividef(1.f, 1.f + __expf(-x)); }
__device__ __forceinline__ float tanhf_(float x){ return 1.f - __fdividef(2.f, __expf(2.f*x) + 1.f); }

__device__ __forceinline__ void gload16(const void* g, void* l) {
#if __has_builtin(__builtin_amdgcn_global_load_lds)
  __builtin_amdgcn_global_load_lds((const __attribute__((address_space(1))) void*)g,
                                   (__attribute__((address_space(3))) void*)l, 16, 0, 0);
#else
  *(uint4*)l = *(const uint4*)g;
#endif
}

// ---------------- converts ----------------
__global__ void cvt_bf16_kernel(const float* __restrict__ in,
                                __hip_bfloat16* __restrict__ out, int n4) {
  int i = blockIdx.x*blockDim.x + threadIdx.x;
  int stride = gridDim.x*blockDim.x;
  for (int j = i; j < n4; j += stride) {
    float4 v = ((const float4*)in)[j];
    __hip_bfloat16 h0 = __float2bfloat16(v.x), h1 = __float2bfloat16(v.y),
                   h2 = __float2bfloat16(v.z), h3 = __float2bfloat16(v.w);
    ushort4 o;
    o.x = __builtin_bit_cast(unsigned short, h0);
    o.y = __builtin_bit_cast(unsigned short, h1);
    o.z = __builtin_bit_cast(unsigned short, h2);
    o.w = __builtin_bit_cast(unsigned short, h3);
    ((ushort4*)out)[j] = o;
  }
}

__global__ void cvt_f16_kernel(const float* __restrict__ in,
                               _Float16* __restrict__ out, int n4) {
  int i = blockIdx.x*blockDim.x + threadIdx.x;
  int stride = gridDim.x*blockDim.x;
  for (int j = i; j < n4; j += stride) {
    float4 v = ((const float4*)in)[j];
    _Float16 h0 = (_Float16)v.x, h1 = (_Float16)v.y,
             h2 = (_Float16)v.z, h3 = (_Float16)v.w;
    ushort4 o;
    o.x = __builtin_bit_cast(unsigned short, h0);
    o.y = __builtin_bit_cast(unsigned short, h1);
    o.z = __builtin_bit_cast(unsigned short, h2);
    o.w = __builtin_bit_cast(unsigned short, h3);
    ((ushort4*)out)[j] = o;
  }
}

__global__ void bias_kernel(const float* __restrict__ bihf, const float* __restrict__ bhhf,
                            const float* __restrict__ bihb, const float* __restrict__ bhhb,
                            float* __restrict__ bias) {
  int i = blockIdx.x*blockDim.x + threadIdx.x;
  if (i < 512)       bias[i] = bihf[i] + bhhf[i];
  else if (i < 1024) bias[i] = bihb[i-512] + bhhb[i-512];
}

// ---------------- xproj GEMM -> gate planes ----------------
// Output layout: xq[(dir*4+gate)][m][j]  (j = h-idx 0..127), bf16, bias folded in.
__global__ __launch_bounds__(256, 2) void gemm_xproj(
    const __hip_bfloat16* __restrict__ A,    // [NM][768]
    const __hip_bfloat16* __restrict__ Bw,   // [1024][768] rows n (B^T layout)
    const float* __restrict__ bias,          // [1024]
    __hip_bfloat16* __restrict__ xq)         // [2*4][NM][128] gate planes
{
  __shared__ __align__(16) __hip_bfloat16 As[128*64];
  __shared__ __align__(16) __hip_bfloat16 Bs[128*64];
  const int bm = blockIdx.x * 128;
  const int bn = blockIdx.y * 128;
  const int tid = threadIdx.x;
  const int lane = tid & 63;
  const int wv = tid >> 6;
  const int wr = wv >> 1, wc = wv & 1;
  char* AsB = (char*)As;
  char* BsB = (char*)Bs;
  const char* Ab = (const char*)A;
  const char* Bb = (const char*)Bw;
  f32x4 acc[4][4] = {};

  for (int kt = 0; kt < 12; ++kt) {
    const int k0 = kt * 64;
    __syncthreads();                  // prev compute done before overwrite
    #pragma unroll
    for (int i = 0; i < 4; ++i) {
      int fb = i*4096 + tid*16;       // byte within 16KB tile
      int r  = fb >> 7;               // row (128B per row of 64 bf16)
      int cb = fb & 127;              // byte within row
      gload16(Ab + ((size_t)(bm + r)*768 + k0)*2 + cb, AsB + fb);
      gload16(Bb + ((size_t)(bn + r)*768 + k0)*2 + cb, BsB + fb);
    }
    __syncthreads();
    #pragma unroll
    for (int ks = 0; ks < 2; ++ks) {
      const int krow = ks*32 + ((lane >> 4) << 3);
      short8 af[4], bfr[4];
      #pragma unroll
      for (int m = 0; m < 4; ++m) {
        int row = wr*64 + m*16 + (lane & 15);
        af[m] = *(const short8*)(AsB + (row*64 + krow)*2);
      }
      #pragma unroll
      for (int n = 0; n < 4; ++n) {
        int row = wc*64 + n*16 + (lane & 15);
        bfr[n] = *(const short8*)(BsB + (row*64 + krow)*2);
      }
      #pragma unroll
      for (int m = 0; m < 4; ++m)
        #pragma unroll
        for (int n = 0; n < 4; ++n)
          acc[m][n] = __builtin_amdgcn_mfma_f32_16x16x32_bf16(af[m], bfr[n], acc[m][n], 0, 0, 0);
    }
  }
  // epilogue: C/D layout col=lane&15, row=(lane>>4)*4+reg; scatter to gate planes
  #pragma unroll
  for (int m = 0; m < 4; ++m) {
    #pragma unroll
    for (int n = 0; n < 4; ++n) {
      const int col = bn + wc*64 + n*16 + (lane & 15);
      const float bv = bias[col];
      const int dir = col >> 9;
      const int cc  = col & 511;
      const int g   = cc >> 7;
      const int jc  = cc & 127;
      __hip_bfloat16* dst = xq + ((size_t)(dir*4 + g)*NM)*128 + jc;
      #pragma unroll
      for (int jj = 0; jj < 4; ++jj) {
        const int row = bm + wr*64 + m*16 + ((lane >> 4)*4 + jj);
        dst[(size_t)row*128] = __float2bfloat16(acc[m][n][jj] + bv);
        dst += 0;  // (kept simple; indexing below)
      }
      // NOTE: the loop above must index per-row; rewritten explicitly:
      #pragma unroll
      for (int jj = 0; jj < 4; ++jj) { (void)jj; }
    }
  }
}

// The epilogue above had a latent indexing bug risk; use a corrected kernel instead.
__global__ __launch_bounds__(256, 2) void gemm_xproj2(
    const __hip_bfloat16* __restrict__ A,
    const __hip_bfloat16* __restrict__ Bw,
    const float* __restrict__ bias,
    __hip_bfloat16* __restrict__ xq)
{
  __shared__ __align__(16) __hip_bfloat16 As[128*64];
  __shared__ __align__(16) __hip_bfloat16 Bs[128*64];
  const int bm = blockIdx.x * 128;
  const int bn = blockIdx.y * 128;
  const int tid = threadIdx.x;
  const int lane = tid & 63;
  const int wv = tid >> 6;
  const int wr = wv >> 1, wc = wv & 1;
  char* AsB = (char*)As;
  char* BsB = (char*)Bs;
  const char* Ab = (const char*)A;
  const char* Bb = (const char*)Bw;
  f32x4 acc[4][4] = {};

  for (int kt = 0; kt < 12; ++kt) {
    const int k0 = kt * 64;
    __syncthreads();
    #pragma unroll
    for (int i = 0; i < 4; ++i) {
      int fb = i*4096 + tid*16;
      int r  = fb >> 7;
      int cb = fb & 127;
      gload16(Ab + ((size_t)(bm + r)*768 + k0)*2 + cb, AsB + fb);
      gload16(Bb + ((size_t)(bn + r)*768 + k0)*2 + cb, BsB + fb);
    }
    __syncthreads();
    #pragma unroll
    for (int ks = 0; ks < 2; ++ks) {
      const int krow = ks*32 + ((lane >> 4) << 3);
      short8 af[4], bfr[4];
      #pragma unroll
      for (int m = 0; m < 4; ++m) {
        int row = wr*64 + m*16 + (lane & 15);
        af[m] = *(const short8*)(AsB + (row*64 + krow)*2);
      }
      #pragma unroll
      for (int n = 0; n < 4; ++n) {
        int row = wc*64 + n*16 + (lane & 15);
        bfr[n] = *(const short8*)(BsB + (row*64 + krow)*2);
      }
      #pragma unroll
      for (int m = 0; m < 4; ++m)
        #pragma unroll
        for (int n = 0; n < 4; ++n)
          acc[m][n] = __builtin_amdgcn_mfma_f32_16x16x32_bf16(af[m], bfr[n], acc[m][n], 0, 0, 0);
    }
  }
  #pragma unroll
  for (int m = 0; m < 4; ++m) {
    #pragma unroll
    for (int n = 0; n < 4; ++n) {
      const int col = bn + wc*64 + n*16 + (lane & 15);
      const float bv = bias[col];
      const int dir = col >> 9;
      const int cc  = col & 511;
      const int g   = cc >> 7;
      const int jc  = cc & 127;
      __hip_bfloat16* plane = xq + ((size_t)(dir*4 + g)*NM)*128;
      #pragma unroll
      for (int jj = 0; jj < 4; ++jj) {
        const int row = bm + wr*64 + m*16 + ((lane >> 4)*4 + jj);
        plane[(size_t)row*128 + jc] = __float2bfloat16(acc[m][n][jj] + bv);
      }
    }
  }
}

// ---------------- LSTM recurrence: 64 blocks = (dir, b) chains, 512 threads ----------------
// thread = (j = t>>2 in [0,128), q = t&3 k-quarter). Thread computes all 4 gates
// for h-index j over k in [q*32, q*32+32); butterfly shfl_xor(1,2) over q completes
// the k-reduction; all 4 quad lanes then compute identical c,h.
__global__ __attribute__((amdgpu_waves_per_eu(2, 2))) __launch_bounds__(512)
void lstm_kernel(
    const __hip_bfloat16* __restrict__ xq,   // [2*4][NM][128] gate planes
    const _Float16* __restrict__ whh16,      // [2][512][128]
    float* __restrict__ hf,                  // [NM][128]
    float* __restrict__ hb)                  // [NM][128]
{
  __shared__ __align__(16) _Float16 hsh[2][128];
  const int bid = blockIdx.x;
  const int dir = bid >> 5, b = bid & 31;
  const int t = threadIdx.x;
  const int j = t >> 2, q = t & 3;

  // weights: 4 gate-rows x 16 f16-pairs (this thread's k-quarter) = 64 dwords
  unsigned int wgt[4][16];
  #pragma unroll
  for (int g = 0; g < 4; ++g) {
    const uint4* wp = (const uint4*)(whh16 + ((size_t)dir*512 + g*128 + j)*128 + q*32);
    #pragma unroll
    for (int i = 0; i < 4; ++i) {
      uint4 v = wp[i];
      wgt[g][i*4+0] = v.x; wgt[g][i*4+1] = v.y; wgt[g][i*4+2] = v.z; wgt[g][i*4+3] = v.w;
    }
  }
  #pragma unroll
  for (int g = 0; g < 4; ++g)
    #pragma unroll
    for (int p = 0; p < 16; ++p)
      asm volatile("" : "+v"(wgt[g][p]));

  if (q == 0) hsh[0][j] = (_Float16)0.f;
  __syncthreads();

  const __hip_bfloat16* xpl[4];
  #pragma unroll
  for (int g = 0; g < 4; ++g)
    xpl[g] = xq + (((size_t)(dir*4 + g)*NM + (size_t)b*512))*128 + j;

  float* hout = (dir ? hb : hf) + (size_t)b*512*128;

  float c = 0.f;
  int rb = 0;

  // depth-2 x prefetch (per-gate bf16 scalars)
  unsigned short xc[4], xn[4];
  {
    const int s0 = dir ? 511 : 0;
    const int s1 = dir ? 510 : 1;
    #pragma unroll
    for (int g = 0; g < 4; ++g) {
      xc[g] = *(const unsigned short*)(xpl[g] + (size_t)s0*128);
      xn[g] = *(const unsigned short*)(xpl[g] + (size_t)s1*128);
    }
  }

  for (int si = 0; si < 512; ++si) {
    const int s = dir ? (511 - si) : si;
    unsigned short xu[4] = {xc[0], xc[1], xc[2], xc[3]};
    #pragma unroll
    for (int g = 0; g < 4; ++g) xc[g] = xn[g];
    if (si + 2 < 512) {
      const int sn = dir ? (509 - si) : (si + 2);
      #pragma unroll
      for (int g = 0; g < 4; ++g)
        xn[g] = *(const unsigned short*)(xpl[g] + (size_t)sn*128);
    }

    const uint4* h4 = (const uint4*)(&hsh[rb][q*32]);
    uint4 hA = h4[0], hB = h4[1], hC = h4[2], hD = h4[3];
    const unsigned int hq[16] = {hA.x,hA.y,hA.z,hA.w, hB.x,hB.y,hB.z,hB.w,
                                 hC.x,hC.y,hC.z,hC.w, hD.x,hD.y,hD.z,hD.w};
    float a0 = 0.f, a1 = 0.f, a2 = 0.f, a3 = 0.f;
    #pragma unroll
    for (int p = 0; p < 16; ++p) {
      const unsigned int hv = hq[p];
      a0 = fd2(wgt[0][p], hv, a0);
      a1 = fd2(wgt[1][p], hv, a1);
      a2 = fd2(wgt[2][p], hv, a2);
      a3 = fd2(wgt[3][p], hv, a3);
    }
    // butterfly over the quad's k-quarters (all 4 lanes end identical)
    a0 += __shfl_xor(a0, 1, 64); a1 += __shfl_xor(a1, 1, 64);
    a2 += __shfl_xor(a2, 1, 64); a3 += __shfl_xor(a3, 1, 64);
    a0 += __shfl_xor(a0, 2, 64); a1 += __shfl_xor(a1, 2, 64);
    a2 += __shfl_xor(a2, 2, 64); a3 += __shfl_xor(a3, 2, 64);

    const float zi = a0 + bfu(xu[0]);
    const float zf = a1 + bfu(xu[1]);
    const float zg = a2 + bfu(xu[2]);
    const float zo = a3 + bfu(xu[3]);

    c = sigf(zf)*c + sigf(zi)*tanhf_(zg);
    const float h = sigf(zo)*tanhf_(c);

    const int wb = rb ^ 1;
    if (q == 0)      hsh[wb][j] = (_Float16)h;
    else if (q == 1) hout[(size_t)s*128 + j] = h;
    __syncthreads();
    rb = wb;
  }
}

// ---------------- emissions: em[m][t] = [hf|hb][m] . Wp[t] + bp[t] ----------------
__global__ __launch_bounds__(256) void em_kernel(
    const float* __restrict__ hf, const float* __restrict__ hb,
    const float* __restrict__ Wp, const float* __restrict__ bp,
    float* __restrict__ em)
{
  __shared__ float wps[15*256];
  __shared__ float bps[15];
  const int tid = threadIdx.x;
  for (int i = tid; i < 15*256; i += 256) wps[i] = Wp[i];
  if (tid < 15) bps[tid] = bp[tid];
  __syncthreads();
  const size_t m = (size_t)blockIdx.x*256 + tid;
  float acc[15];
  #pragma unroll
  for (int t2 = 0; t2 < 15; ++t2) acc[t2] = bps[t2];
  const float4* hf4 = (const float4*)(hf + m*128);
  const float4* hb4 = (const float4*)(hb + m*128);
  for (int kc = 0; kc < 32; ++kc) {
    float4 hv = hf4[kc];
    #pragma unroll
    for (int t2 = 0; t2 < 15; ++t2)
      acc[t2] += hv.x*wps[t2*256 + kc*4+0] + hv.y*wps[t2*256 + kc*4+1]
               + hv.z*wps[t2*256 + kc*4+2] + hv.w*wps[t2*256 + kc*4+3];
  }
  for (int kc = 0; kc < 32; ++kc) {
    float4 hv = hb4[kc];
    #pragma unroll
    for (int t2 = 0; t2 < 15; ++t2)
      acc[t2] += hv.x*wps[t2*256 + 128 + kc*4+0] + hv.y*wps[t2*256 + 128 + kc*4+1]
               + hv.z*wps[t2*256 + 128 + kc*4+2] + hv.w*wps[t2*256 + 128 + kc*4+3];
  }
  float* eo = em + m*15;
  #pragma unroll
  for (int t2 = 0; t2 < 15; ++t2) eo[t2] = acc[t2];
}

// ---------------- CRF NLL: one block (1 wave) per batch -> partial per b ----------------
__global__ __launch_bounds__(64) void crf_kernel(
    const float* __restrict__ em,    // [NM][15]
    const int* __restrict__ tags, const int* __restrict__ mask,
    const float* __restrict__ trans, const float* __restrict__ start_t,
    const float* __restrict__ end_t, float* __restrict__ nllb)
{
  __shared__ __align__(16) float ems[512*15];
  __shared__ float trs[225];
  __shared__ int tgs[512];
  __shared__ int mks[512];
  const int b = blockIdx.x, j = threadIdx.x;
  const float* emb = em + (size_t)b*512*15;
  {
    const float4* s4 = (const float4*)emb;
    float4* d4 = (float4*)ems;
    for (int i = j; i < 512*15/4; i += 64) d4[i] = s4[i];
    for (int i = j; i < 512; i += 64) { tgs[i] = tags[b*512+i]; mks[i] = mask[b*512+i]; }
    for (int i = j; i < 225; i += 64) trs[i] = trans[i];
  }
  __syncthreads();

  float trc[15];
  #pragma unroll
  for (int i = 0; i < 15; ++i) trc[i] = (j < 15) ? trs[i*15 + j] : 0.f;

  float alpha = (j < 15) ? (start_t[j] + ems[j]) : -3.0e38f;
  for (int s = 1; s < 512; ++s) {
    const float emv = (j < 15) ? ems[s*15 + j] : 0.f;
    const int msk = mks[s];
    float v[15];
    #pragma unroll
    for (int i = 0; i < 15; ++i) {
      const float ai = __shfl(alpha, i, 64);
      v[i] = ai + trc[i];
    }
    const float t01 = fmaxf(v[0], v[1]),  t23 = fmaxf(v[2], v[3]);
    const float t45 = fmaxf(v[4], v[5]),  t67 = fmaxf(v[6], v[7]);
    const float t89 = fmaxf(v[8], v[9]),  tab = fmaxf(v[10], v[11]);
    const float tcd = fmaxf(v[12], v[13]);
    const float q0 = fmaxf(t01, t23), q1 = fmaxf(t45, t67);
    const float q2 = fmaxf(t89, tab), q3 = fmaxf(tcd, v[14]);
    const float mx = fmaxf(fmaxf(q0, q1), fmaxf(q2, q3));
    float e[15];
    #pragma unroll
    for (int i = 0; i < 15; ++i) e[i] = __expf(v[i] - mx);
    const float s01 = e[0]+e[1], s23 = e[2]+e[3], s45 = e[4]+e[5], s67 = e[6]+e[7];
    const float s89 = e[8]+e[9], sab = e[10]+e[11], scd = e[12]+e[13];
    const float u0 = s01+s23, u1 = s45+s67, u2 = s89+sab, u3 = scd+e[14];
    const float sum = (u0+u1) + (u2+u3);
    const float nxt = emv + mx + __logf(sum);
    if (msk > 0 && j < 15) alpha = nxt;
  }
  float vz = (j < 15) ? (alpha + end_t[j]) : -3.0e38f;
  float mz = vz;
  #pragma unroll
  for (int off = 32; off > 0; off >>= 1) mz = fmaxf(mz, __shfl_xor(mz, off, 64));
  float se = (j < 15) ? __expf(vz - mz) : 0.f;
  #pragma unroll
  for (int off = 32; off > 0; off >>= 1) se += __shfl_xor(se, off, 64);
  const float logZ = mz + __logf(se);

  float sc = 0.f; int cnt = 0;
  for (int s = j; s < 512; s += 64) cnt += (mks[s] ? 1 : 0);
  for (int s = 1 + j; s < 512; s += 64) {
    if (mks[s]) {
      const int tp = tgs[s-1], tc = tgs[s];
      sc += trs[tp*15 + tc] + ems[s*15 + tc];
    }
  }
  #pragma unroll
  for (int off = 32; off > 0; off >>= 1) {
    sc  += __shfl_xor(sc, off, 64);
    cnt += __shfl_xor(cnt, off, 64);
  }
  if (j == 0) {
    const int t0 = tgs[0];
    sc += start_t[t0] + ems[t0];
    int last = cnt - 1; if (last < 0) last = 0;
    sc += end_t[tgs[last]];
    nllb[b] = logZ - sc;
  }
}

__global__ __launch_bounds__(64) void nll_reduce_kernel(const float* __restrict__ nllb,
                                                        float* __restrict__ out) {
  const int j = threadIdx.x;
  float v = (j < 32) ? nllb[j] : 0.f;
  #pragma unroll
  for (int off = 32; off > 0; off >>= 1) v += __shfl_xor(v, off, 64);
  if (j == 0) out[0] = v;
}

// ---------------- launch ----------------
extern "C" void kernel_launch(void* const* d_in, const int* in_sizes, int n_in,
                              void* d_out, int out_size, void* d_ws, size_t ws_size,
                              hipStream_t stream) {
  const float* x      = (const float*)d_in[0];
  const int*   tags   = (const int*)d_in[1];
  const int*   mask   = (const int*)d_in[2];
  const float* Wih_f  = (const float*)d_in[3];
  const float* Whh_f  = (const float*)d_in[4];
  const float* bih_f  = (const float*)d_in[5];
  const float* bhh_f  = (const float*)d_in[6];
  const float* Wih_b  = (const float*)d_in[7];
  const float* Whh_b  = (const float*)d_in[8];
  const float* bih_b  = (const float*)d_in[9];
  const float* bhh_b  = (const float*)d_in[10];
  const float* Wp     = (const float*)d_in[11];
  const float* bp     = (const float*)d_in[12];
  const float* trans  = (const float*)d_in[13];
  const float* start_t= (const float*)d_in[14];
  const float* end_t  = (const float*)d_in[15];
  float* out = (float*)d_out;

  char* ws = (char*)d_ws;
  size_t off = 0;
  auto alloc = [&](size_t bytes) { char* p = ws + off; off += (bytes + 255) & ~(size_t)255; return p; };
  __hip_bfloat16* xbf   = (__hip_bfloat16*)alloc((size_t)NM*NE*2);
  __hip_bfloat16* Wihbf = (__hip_bfloat16*)alloc((size_t)1024*NE*2);
  _Float16*       whh16 = (_Float16*)alloc((size_t)2*512*128*2);
  float*          bias  = (float*)alloc(1024*4);
  __hip_bfloat16* xq    = (__hip_bfloat16*)alloc((size_t)8*NM*128*2);
  float*          hf    = (float*)alloc((size_t)NM*128*4);
  float*          hb    = (float*)alloc((size_t)NM*128*4);
  float*          em    = (float*)alloc((size_t)NM*15*4);
  float*          nllb  = (float*)alloc(32*4);
  (void)ws_size; (void)in_sizes; (void)n_in; (void)out_size;

  cvt_bf16_kernel<<<2048, 256, 0, stream>>>(x, xbf, NM*NE/4);
  cvt_bf16_kernel<<<256, 256, 0, stream>>>(Wih_f, Wihbf, 512*768/4);
  cvt_bf16_kernel<<<256, 256, 0, stream>>>(Wih_b, Wihbf + 512*768, 512*768/4);
  cvt_f16_kernel<<<64, 256, 0, stream>>>(Whh_f, whh16, 512*128/4);
  cvt_f16_kernel<<<64, 256, 0, stream>>>(Whh_b, whh16 + 512*128, 512*128/4);
  bias_kernel<<<4, 256, 0, stream>>>(bih_f, bhh_f, bih_b, bhh_b, bias);

  gemm_xproj2<<<dim3(128, 8), 256, 0, stream>>>(xbf, Wihbf, bias, xq);
  lstm_kernel<<<64, 512, 0, stream>>>(xq, whh16, hf, hb);
  em_kernel<<<64, 256, 0, stream>>>(hf, hb, Wp, bp, em);
  crf_kernel<<<32, 64, 0, stream>>>(em, tags, mask, trans, start_t, end_t, nllb);
  nll_reduce_kernel<<<1, 64, 0, stream>>>(nllb, out);
}

// Round 4
// 735.165 us; speedup vs baseline: 1.1080x; 1.0066x over previous
//
#include <hip/hip_runtime.h>
#include <hip/hip_bf16.h>
#include <cstdint>

typedef __attribute__((ext_vector_type(8))) short short8;
typedef __attribute__((ext_vector_type(4))) float f32x4;

#define NS 512
#define NB 32
#define NE 768
#define NH 128
#define NT 15
#define NM (NB*NS)      // 16384 rows, m = b*512 + s

__device__ __forceinline__ float bflo(unsigned int u){ return __builtin_bit_cast(float, u << 16); }
__device__ __forceinline__ float bfhi(unsigned int u){ return __builtin_bit_cast(float, u & 0xffff0000u); }
__device__ __forceinline__ float sigf(float x){ return __fdividef(1.f, 1.f + __expf(-x)); }
__device__ __forceinline__ float tanhf_(float x){ return 1.f - __fdividef(2.f, __expf(2.f*x) + 1.f); }

__device__ __forceinline__ void gload16(const void* g, void* l) {
#if __has_builtin(__builtin_amdgcn_global_load_lds)
  __builtin_amdgcn_global_load_lds((const __attribute__((address_space(1))) void*)g,
                                   (__attribute__((address_space(3))) void*)l, 16, 0, 0);
#else
  *(uint4*)l = *(const uint4*)g;
#endif
}

// ---------------- converts ----------------
__global__ void cvt_bf16_kernel(const float* __restrict__ in,
                                __hip_bfloat16* __restrict__ out, int n4) {
  int i = blockIdx.x*blockDim.x + threadIdx.x;
  int stride = gridDim.x*blockDim.x;
  for (int j = i; j < n4; j += stride) {
    float4 v = ((const float4*)in)[j];
    ushort4 o;
    o.x = __builtin_bit_cast(unsigned short, __float2bfloat16(v.x));
    o.y = __builtin_bit_cast(unsigned short, __float2bfloat16(v.y));
    o.z = __builtin_bit_cast(unsigned short, __float2bfloat16(v.z));
    o.w = __builtin_bit_cast(unsigned short, __float2bfloat16(v.w));
    ((ushort4*)out)[j] = o;
  }
}

// permuted row n = dir*512 + (j*4+g)  <- src row (g*128+j) of dir's weight
__global__ void cvt_wih_perm(const float* __restrict__ wf, const float* __restrict__ wb,
                             __hip_bfloat16* __restrict__ out) {
  const int n = blockIdx.x;           // 0..1023
  const int dir = n >> 9, cc = n & 511, j = cc >> 2, g = cc & 3;
  const float* src = (dir ? wb : wf) + (size_t)(g*128 + j)*768;
  __hip_bfloat16* dst = out + (size_t)n*768;
  for (int e = threadIdx.x; e < 768; e += 256) dst[e] = __float2bfloat16(src[e]);
}

__global__ void cvt_whh_perm(const float* __restrict__ wf, const float* __restrict__ wb,
                             __hip_bfloat16* __restrict__ out) {
  const int n = blockIdx.x;           // 0..1023 = dir*512+cc
  const int dir = n >> 9, cc = n & 511, j = cc >> 2, g = cc & 3;
  const float* src = (dir ? wb : wf) + (size_t)(g*128 + j)*128;
  __hip_bfloat16* dst = out + (size_t)n*128;
  if (threadIdx.x < 128) dst[threadIdx.x] = __float2bfloat16(src[threadIdx.x]);
}

__global__ void bias_perm_kernel(const float* __restrict__ bihf, const float* __restrict__ bhhf,
                                 const float* __restrict__ bihb, const float* __restrict__ bhhb,
                                 float* __restrict__ biasp) {
  const int n = blockIdx.x*blockDim.x + threadIdx.x;
  if (n >= 1024) return;
  const int dir = n >> 9, cc = n & 511, j = cc >> 2, g = cc & 3;
  const int src = g*128 + j;
  biasp[n] = dir ? (bihb[src] + bhhb[src]) : (bihf[src] + bhhf[src]);
}

// ---------------- xproj GEMM: A[16384x768] @ Bw[1024x768]^T -> xqd[2][NM][512] ----------------
// Bw rows already permuted: n = dir*512 + (j*4+g). Bias folded.
__global__ __launch_bounds__(256, 2) void gemm_xproj(
    const __hip_bfloat16* __restrict__ A,
    const __hip_bfloat16* __restrict__ Bw,
    const float* __restrict__ biasp,
    __hip_bfloat16* __restrict__ xqd)        // [2][NM][512]
{
  __shared__ __align__(16) __hip_bfloat16 As[128*64];
  __shared__ __align__(16) __hip_bfloat16 Bs[128*64];
  const int bm = blockIdx.x * 128;
  const int bn = blockIdx.y * 128;
  const int tid = threadIdx.x;
  const int lane = tid & 63;
  const int wv = tid >> 6;
  const int wr = wv >> 1, wc = wv & 1;
  char* AsB = (char*)As;
  char* BsB = (char*)Bs;
  const char* Ab = (const char*)A;
  const char* Bb = (const char*)Bw;
  f32x4 acc[4][4] = {};

  for (int kt = 0; kt < 12; ++kt) {
    const int k0 = kt * 64;
    __syncthreads();
    #pragma unroll
    for (int i = 0; i < 4; ++i) {
      int fb = i*4096 + tid*16;
      int r  = fb >> 7;
      int cb = fb & 127;
      gload16(Ab + ((size_t)(bm + r)*768 + k0)*2 + cb, AsB + fb);
      gload16(Bb + ((size_t)(bn + r)*768 + k0)*2 + cb, BsB + fb);
    }
    __syncthreads();
    #pragma unroll
    for (int ks = 0; ks < 2; ++ks) {
      const int krow = ks*32 + ((lane >> 4) << 3);
      short8 af[4], bfr[4];
      #pragma unroll
      for (int m = 0; m < 4; ++m) {
        int row = wr*64 + m*16 + (lane & 15);
        af[m] = *(const short8*)(AsB + (row*64 + krow)*2);
      }
      #pragma unroll
      for (int n = 0; n < 4; ++n) {
        int row = wc*64 + n*16 + (lane & 15);
        bfr[n] = *(const short8*)(BsB + (row*64 + krow)*2);
      }
      #pragma unroll
      for (int m = 0; m < 4; ++m)
        #pragma unroll
        for (int n = 0; n < 4; ++n)
          acc[m][n] = __builtin_amdgcn_mfma_f32_16x16x32_bf16(af[m], bfr[n], acc[m][n], 0, 0, 0);
    }
  }
  #pragma unroll
  for (int m = 0; m < 4; ++m) {
    #pragma unroll
    for (int n = 0; n < 4; ++n) {
      const int col = bn + wc*64 + n*16 + (lane & 15);
      const float bv = biasp[col];
      const int dir = col >> 9;
      const int cc  = col & 511;
      #pragma unroll
      for (int jj = 0; jj < 4; ++jj) {
        const int row = bm + wr*64 + m*16 + ((lane >> 4)*4 + jj);
        xqd[((size_t)dir*NM + row)*512 + cc] = __float2bfloat16(acc[m][n][jj] + bv);
      }
    }
  }
}

// ---------------- LSTM recurrence via MFMA ----------------
// 16 blocks = (dir 0..1) x (bg 0..7), each handles 4 batches. 512 threads = 8 waves.
// Per step: z[512 rows x 16 cols] = Whhp[512x128] @ h[128x16] via MFMA (cols 4..15 zero-padded).
// Row encoding: row = j*4 + gate -> each lane's 4 acc regs = 4 gates of one (j,b).
__global__ __launch_bounds__(512, 2) void lstm_mfma(
    const __hip_bfloat16* __restrict__ xqd,   // [2][NM][512] packed j*4+g, bias folded
    const __hip_bfloat16* __restrict__ whhp,  // [2][512][128] permuted rows
    float* __restrict__ hf,                   // [NM][128]
    float* __restrict__ hb)                   // [NM][128]
{
  __shared__ __align__(16) __hip_bfloat16 h_lds[16*136];   // rows n (batch slot), stride 136
  __shared__ __align__(16) float z_lds[4*516];             // rows b (real batch), stride 516

  const int bid = blockIdx.x;
  const int dir = bid >> 3, bg = bid & 7;
  const int t = threadIdx.x;
  const int w = t >> 6, l = t & 63;
  const int ln = l & 15, lp = l >> 4;

  // A-fragments: wave w owns rtiles w*4+r; 64 dwords/lane, pinned resident.
  uint4 afu[4][4];
  {
    const char* wb = (const char*)(whhp + (size_t)dir*512*128);
    #pragma unroll
    for (int r = 0; r < 4; ++r) {
      const int row = (w*4 + r)*16 + ln;
      #pragma unroll
      for (int kc = 0; kc < 4; ++kc)
        afu[r][kc] = *(const uint4*)(wb + ((size_t)row*128 + lp*8 + kc*32)*2);
    }
  }

  for (int i = t; i < 16*136; i += 512) h_lds[i] = __hip_bfloat16(0.f);

  // phase-B identity: j = t&127, b = t>>7
  const int j = t & 127, b = t >> 7;
  const __hip_bfloat16* xp = xqd + ((size_t)dir*NM + (size_t)(bg*4 + b)*512)*512 + j*4;
  float* hout = (dir ? hb : hf) + ((size_t)(bg*4 + b)*512)*128 + j;

  float c = 0.f;
  uint2 xc, xn;
  {
    const int s0 = dir ? 511 : 0;
    const int s1 = dir ? 510 : 1;
    xc = *(const uint2*)(xp + (size_t)s0*512);
    xn = *(const uint2*)(xp + (size_t)s1*512);
  }
  __syncthreads();

  const char* hbase = (const char*)h_lds;

  for (int si = 0; si < 512; ++si) {
    const int s = dir ? (511 - si) : si;

    // pin A-frags (prevents load rematerialization into the loop)
    #pragma unroll
    for (int r = 0; r < 4; ++r)
      #pragma unroll
      for (int kc = 0; kc < 4; ++kc)
        asm volatile("" : "+v"(afu[r][kc].x), "+v"(afu[r][kc].y),
                          "+v"(afu[r][kc].z), "+v"(afu[r][kc].w));

    // B-fragments from h_lds (rows n = batch slot, k contiguous)
    short8 bfv[4];
    #pragma unroll
    for (int kc = 0; kc < 4; ++kc)
      bfv[kc] = *(const short8*)(hbase + ln*272 + (lp*8 + kc*32)*2);

    f32x4 acc[4];
    #pragma unroll
    for (int r = 0; r < 4; ++r) {
      acc[r] = f32x4{0.f, 0.f, 0.f, 0.f};
      #pragma unroll
      for (int kc = 0; kc < 4; ++kc)
        acc[r] = __builtin_amdgcn_mfma_f32_16x16x32_bf16(
                   __builtin_bit_cast(short8, afu[r][kc]), bfv[kc], acc[r], 0, 0, 0);
    }

    // prefetch xq for si+2
    uint2 x2 = xn;
    if (si + 2 < 512) {
      const int sn = dir ? (509 - si) : (si + 2);
      x2 = *(const uint2*)(xp + (size_t)sn*512);
    }

    // publish z for real batch slots
    if (ln < 4) {
      #pragma unroll
      for (int r = 0; r < 4; ++r) {
        const int jw = (w*4 + r)*4 + lp;
        *(f32x4*)&z_lds[ln*516 + jw*4] = acc[r];
      }
    }
    __syncthreads();

    // phase B: one h per thread
    const f32x4 zv = *(const f32x4*)&z_lds[b*516 + j*4];
    const float zi = zv[0] + bflo(xc.x);
    const float zf = zv[1] + bfhi(xc.x);
    const float zg = zv[2] + bflo(xc.y);
    const float zo = zv[3] + bfhi(xc.y);
    c = sigf(zf)*c + sigf(zi)*tanhf_(zg);
    const float h = sigf(zo)*tanhf_(c);

    h_lds[b*136 + j] = __float2bfloat16(h);
    hout[(size_t)s*128] = h;
    xc = xn; xn = x2;
    __syncthreads();
  }
}

// ---------------- emissions: em[m][t] = [hf|hb][m] . Wp[t] + bp[t] ----------------
__global__ __launch_bounds__(256) void em_kernel(
    const float* __restrict__ hf, const float* __restrict__ hb,
    const float* __restrict__ Wp, const float* __restrict__ bp,
    float* __restrict__ em)
{
  __shared__ float wps[15*256];
  __shared__ float bps[15];
  const int tid = threadIdx.x;
  for (int i = tid; i < 15*256; i += 256) wps[i] = Wp[i];
  if (tid < 15) bps[tid] = bp[tid];
  __syncthreads();
  const size_t m = (size_t)blockIdx.x*256 + tid;
  float acc[15];
  #pragma unroll
  for (int t2 = 0; t2 < 15; ++t2) acc[t2] = bps[t2];
  const float4* hf4 = (const float4*)(hf + m*128);
  const float4* hb4 = (const float4*)(hb + m*128);
  for (int kc = 0; kc < 32; ++kc) {
    float4 hv = hf4[kc];
    #pragma unroll
    for (int t2 = 0; t2 < 15; ++t2)
      acc[t2] += hv.x*wps[t2*256 + kc*4+0] + hv.y*wps[t2*256 + kc*4+1]
               + hv.z*wps[t2*256 + kc*4+2] + hv.w*wps[t2*256 + kc*4+3];
  }
  for (int kc = 0; kc < 32; ++kc) {
    float4 hv = hb4[kc];
    #pragma unroll
    for (int t2 = 0; t2 < 15; ++t2)
      acc[t2] += hv.x*wps[t2*256 + 128 + kc*4+0] + hv.y*wps[t2*256 + 128 + kc*4+1]
               + hv.z*wps[t2*256 + 128 + kc*4+2] + hv.w*wps[t2*256 + 128 + kc*4+3];
  }
  float* eo = em + m*15;
  #pragma unroll
  for (int t2 = 0; t2 < 15; ++t2) eo[t2] = acc[t2];
}

// ---------------- CRF NLL: one block (1 wave) per batch -> partial per b ----------------
__global__ __launch_bounds__(64) void crf_kernel(
    const float* __restrict__ em,
    const int* __restrict__ tags, const int* __restrict__ mask,
    const float* __restrict__ trans, const float* __restrict__ start_t,
    const float* __restrict__ end_t, float* __restrict__ nllb)
{
  __shared__ __align__(16) float ems[512*15];
  __shared__ float trs[225];
  __shared__ int tgs[512];
  __shared__ int mks[512];
  const int b = blockIdx.x, j = threadIdx.x;
  const float* emb = em + (size_t)b*512*15;
  {
    const float4* s4 = (const float4*)emb;
    float4* d4 = (float4*)ems;
    for (int i = j; i < 512*15/4; i += 64) d4[i] = s4[i];
    for (int i = j; i < 512; i += 64) { tgs[i] = tags[b*512+i]; mks[i] = mask[b*512+i]; }
    for (int i = j; i < 225; i += 64) trs[i] = trans[i];
  }
  __syncthreads();

  float trc[15];
  #pragma unroll
  for (int i = 0; i < 15; ++i) trc[i] = (j < 15) ? trs[i*15 + j] : 0.f;

  float alpha = (j < 15) ? (start_t[j] + ems[j]) : -3.0e38f;
  for (int s = 1; s < 512; ++s) {
    const float emv = (j < 15) ? ems[s*15 + j] : 0.f;
    const int msk = mks[s];
    float v[15];
    #pragma unroll
    for (int i = 0; i < 15; ++i) {
      const float ai = __shfl(alpha, i, 64);
      v[i] = ai + trc[i];
    }
    const float t01 = fmaxf(v[0], v[1]),  t23 = fmaxf(v[2], v[3]);
    const float t45 = fmaxf(v[4], v[5]),  t67 = fmaxf(v[6], v[7]);
    const float t89 = fmaxf(v[8], v[9]),  tab = fmaxf(v[10], v[11]);
    const float tcd = fmaxf(v[12], v[13]);
    const float q0 = fmaxf(t01, t23), q1 = fmaxf(t45, t67);
    const float q2 = fmaxf(t89, tab), q3 = fmaxf(tcd, v[14]);
    const float mx = fmaxf(fmaxf(q0, q1), fmaxf(q2, q3));
    float e[15];
    #pragma unroll
    for (int i = 0; i < 15; ++i) e[i] = __expf(v[i] - mx);
    const float s01 = e[0]+e[1], s23 = e[2]+e[3], s45 = e[4]+e[5], s67 = e[6]+e[7];
    const float s89 = e[8]+e[9], sab = e[10]+e[11], scd = e[12]+e[13];
    const float u0 = s01+s23, u1 = s45+s67, u2 = s89+sab, u3 = scd+e[14];
    const float sum = (u0+u1) + (u2+u3);
    const float nxt = emv + mx + __logf(sum);
    if (msk > 0 && j < 15) alpha = nxt;
  }
  float vz = (j < 15) ? (alpha + end_t[j]) : -3.0e38f;
  float mz = vz;
  #pragma unroll
  for (int off = 32; off > 0; off >>= 1) mz = fmaxf(mz, __shfl_xor(mz, off, 64));
  float se = (j < 15) ? __expf(vz - mz) : 0.f;
  #pragma unroll
  for (int off = 32; off > 0; off >>= 1) se += __shfl_xor(se, off, 64);
  const float logZ = mz + __logf(se);

  float sc = 0.f; int cnt = 0;
  for (int s = j; s < 512; s += 64) cnt += (mks[s] ? 1 : 0);
  for (int s = 1 + j; s < 512; s += 64) {
    if (mks[s]) {
      const int tp = tgs[s-1], tc = tgs[s];
      sc += trs[tp*15 + tc] + ems[s*15 + tc];
    }
  }
  #pragma unroll
  for (int off = 32; off > 0; off >>= 1) {
    sc  += __shfl_xor(sc, off, 64);
    cnt += __shfl_xor(cnt, off, 64);
  }
  if (j == 0) {
    const int t0 = tgs[0];
    sc += start_t[t0] + ems[t0];
    int last = cnt - 1; if (last < 0) last = 0;
    sc += end_t[tgs[last]];
    nllb[b] = logZ - sc;
  }
}

__global__ __launch_bounds__(64) void nll_reduce_kernel(const float* __restrict__ nllb,
                                                        float* __restrict__ out) {
  const int j = threadIdx.x;
  float v = (j < 32) ? nllb[j] : 0.f;
  #pragma unroll
  for (int off = 32; off > 0; off >>= 1) v += __shfl_xor(v, off, 64);
  if (j == 0) out[0] = v;
}

// ---------------- launch ----------------
extern "C" void kernel_launch(void* const* d_in, const int* in_sizes, int n_in,
                              void* d_out, int out_size, void* d_ws, size_t ws_size,
                              hipStream_t stream) {
  const float* x      = (const float*)d_in[0];
  const int*   tags   = (const int*)d_in[1];
  const int*   mask   = (const int*)d_in[2];
  const float* Wih_f  = (const float*)d_in[3];
  const float* Whh_f  = (const float*)d_in[4];
  const float* bih_f  = (const float*)d_in[5];
  const float* bhh_f  = (const float*)d_in[6];
  const float* Wih_b  = (const float*)d_in[7];
  const float* Whh_b  = (const float*)d_in[8];
  const float* bih_b  = (const float*)d_in[9];
  const float* bhh_b  = (const float*)d_in[10];
  const float* Wp     = (const float*)d_in[11];
  const float* bp     = (const float*)d_in[12];
  const float* trans  = (const float*)d_in[13];
  const float* start_t= (const float*)d_in[14];
  const float* end_t  = (const float*)d_in[15];
  float* out = (float*)d_out;

  char* ws = (char*)d_ws;
  size_t off = 0;
  auto alloc = [&](size_t bytes) { char* p = ws + off; off += (bytes + 255) & ~(size_t)255; return p; };
  __hip_bfloat16* xbf   = (__hip_bfloat16*)alloc((size_t)NM*NE*2);        // 25.2 MB
  __hip_bfloat16* Wihbf = (__hip_bfloat16*)alloc((size_t)1024*NE*2);      // 1.6 MB
  __hip_bfloat16* whhp  = (__hip_bfloat16*)alloc((size_t)2*512*128*2);    // 0.26 MB
  float*          biasp = (float*)alloc(1024*4);
  __hip_bfloat16* xqd   = (__hip_bfloat16*)alloc((size_t)2*NM*512*2);     // 33.6 MB
  float*          hf    = (float*)alloc((size_t)NM*128*4);                // 8.4 MB
  float*          hb    = (float*)alloc((size_t)NM*128*4);                // 8.4 MB
  float*          em    = (float*)alloc((size_t)NM*15*4);                 // 1.0 MB
  float*          nllb  = (float*)alloc(32*4);
  (void)ws_size; (void)in_sizes; (void)n_in; (void)out_size;

  cvt_bf16_kernel<<<2048, 256, 0, stream>>>(x, xbf, NM*NE/4);
  cvt_wih_perm<<<1024, 256, 0, stream>>>(Wih_f, Wih_b, Wihbf);
  cvt_whh_perm<<<1024, 128, 0, stream>>>(Whh_f, Whh_b, whhp);
  bias_perm_kernel<<<4, 256, 0, stream>>>(bih_f, bhh_f, bih_b, bhh_b, biasp);

  gemm_xproj<<<dim3(128, 8), 256, 0, stream>>>(xbf, Wihbf, biasp, xqd);
  lstm_mfma<<<16, 512, 0, stream>>>(xqd, whhp, hf, hb);
  em_kernel<<<64, 256, 0, stream>>>(hf, hb, Wp, bp, em);
  crf_kernel<<<32, 64, 0, stream>>>(em, tags, mask, trans, start_t, end_t, nllb);
  nll_reduce_kernel<<<1, 64, 0, stream>>>(nllb, out);
}